// Round 7
// baseline (251.717 us; speedup 1.0000x reference)
//
#include <hip/hip_runtime.h>
#include <hip/hip_bf16.h>
#include <math.h>

#define NROWS 8192
#define DDIM  4096
#define NEXP  64

typedef __attribute__((ext_vector_type(8))) short bf16x8;
typedef __attribute__((ext_vector_type(4))) float f32x4;

__device__ inline unsigned short bf16_rne(float f) {
    unsigned u = __builtin_bit_cast(unsigned, f);
    u += 0x7FFF + ((u >> 16) & 1);
    return (unsigned short)(u >> 16);
}

// split 8 fp32 -> hi/lo bf16 fragments (x = hi + lo + r, |r| <= 2^-18|x|)
__device__ inline void split8(const float* xf, bf16x8& hi, bf16x8& lo) {
#pragma unroll
    for (int j = 0; j < 8; j++) {
        const unsigned short h = bf16_rne(xf[j]);
        const float hf = __builtin_bit_cast(float, (unsigned)h << 16);
        hi[j] = (short)h;
        lo[j] = (short)bf16_rne(xf[j] - hf);
    }
}

// Preconvert W (64 x 4096 fp32) into MFMA B-fragment-linear bf16 hi/lo:
// frag elem j of lane l, tile t, k-chunk kc = B[k=kc*32+(l>>4)*8+j][n=t*16+(l&15)]
// at ((kc*4+t)*64+l)*8. ~1 MB total -> L2-resident for the GEMM.
__global__ __launch_bounds__(256) void wfrag_kernel(
    const float* __restrict__ w, unsigned short* __restrict__ whi,
    unsigned short* __restrict__ wlo)
{
    const int kc = blockIdx.x;            // 0..127
    const int t  = threadIdx.x >> 6;      // n-tile 0..3
    const int l  = threadIdx.x & 63;
    const int e  = t * 16 + (l & 15);
    const int k0 = kc * 32 + ((l >> 4) * 8);
    const float* p = w + (size_t)e * DDIM + k0;
    float xf[8];
    *(float4*)&xf[0] = *(const float4*)p;
    *(float4*)&xf[4] = *(const float4*)(p + 4);
    bf16x8 hi, lo;
    split8(xf, hi, lo);
    const size_t off = ((size_t)(kc * 4 + t) * 64 + l) * 8;
    *(bf16x8*)(whi + off) = hi;
    *(bf16x8*)(wlo + off) = lo;
}

// GEMM: no LDS/barriers. Block = 4 waves; wave = 32 rows (2 m-tiles) x 64
// experts. 32 rows/wave doubles B-fragment reuse vs R6 (B VMEM traffic and
// TA line-transactions halve: B was 8KB/step vs x 2KB/step). B single-
// buffered (L2-hit ~200cyc hidden behind split8 VALU); x double-buffered
// (HBM ~900cyc). Per k32-step: 4 x-loads + 8 B-loads + 24 MFMA.
__global__ __launch_bounds__(256) void gemm_partial_kernel(
    const float* __restrict__ x, const unsigned short* __restrict__ whi,
    const unsigned short* __restrict__ wlo, float* __restrict__ part,
    int ksplit)
{
    const int tid = threadIdx.x;
    const int wv  = tid >> 6;           // wave -> 32-row stripe
    const int l   = tid & 63;
    const int q   = l >> 4;             // quad
    const int col = l & 15;
    const int r0  = blockIdx.x * 128 + wv * 32;
    const int kh  = blockIdx.y;
    const int kchunk = DDIM / ksplit;
    const int ksteps = kchunk / 32;
    const int kb  = kh * kchunk;

    // A: lane holds A[m=col][k=q*8+j]; two m-tiles 16 rows apart
    const float* xp0 = x + (size_t)(r0 + col) * DDIM + kb + q * 8;
    const float* xp1 = xp0 + (size_t)16 * DDIM;
    const unsigned short* bhp = whi + ((size_t)(kb / 32) * 4 * 64 + l) * 8;
    const unsigned short* blp = wlo + ((size_t)(kb / 32) * 4 * 64 + l) * 8;

    f32x4 acc[2][4];
#pragma unroll
    for (int m = 0; m < 2; m++)
#pragma unroll
        for (int t = 0; t < 4; t++) acc[m][t] = f32x4{0, 0, 0, 0};

    float xf[2][2][8];                  // [buf][mtile][elem]

    *(float4*)&xf[0][0][0] = *(const float4*)(xp0);
    *(float4*)&xf[0][0][4] = *(const float4*)(xp0 + 4);
    *(float4*)&xf[0][1][0] = *(const float4*)(xp1);
    *(float4*)&xf[0][1][4] = *(const float4*)(xp1 + 4);

    for (int s = 0; s < ksteps; s++) {
        const int cur = s & 1, nxt = cur ^ 1;

        // B for this step (single-buffered; issue first so L2 latency
        // overlaps the split8 VALU below)
        bf16x8 bh[4], bl[4];
        const unsigned short* bhs = bhp + (size_t)s * 4 * 64 * 8;
        const unsigned short* bls = blp + (size_t)s * 4 * 64 * 8;
#pragma unroll
        for (int t = 0; t < 4; t++) {
            bh[t] = *(const bf16x8*)(bhs + (size_t)t * 64 * 8);
            bl[t] = *(const bf16x8*)(bls + (size_t)t * 64 * 8);
        }

        if (s + 1 < ksteps) {           // prefetch next step's x (HBM)
            const float* xn0 = xp0 + (s + 1) * 32;
            const float* xn1 = xp1 + (s + 1) * 32;
            *(float4*)&xf[nxt][0][0] = *(const float4*)(xn0);
            *(float4*)&xf[nxt][0][4] = *(const float4*)(xn0 + 4);
            *(float4*)&xf[nxt][1][0] = *(const float4*)(xn1);
            *(float4*)&xf[nxt][1][4] = *(const float4*)(xn1 + 4);
        }

        bf16x8 ah[2], al[2];
        split8(xf[cur][0], ah[0], al[0]);
        split8(xf[cur][1], ah[1], al[1]);
#pragma unroll
        for (int m = 0; m < 2; m++)
#pragma unroll
            for (int t = 0; t < 4; t++) {
                acc[m][t] = __builtin_amdgcn_mfma_f32_16x16x32_bf16(ah[m], bh[t], acc[m][t], 0, 0, 0);
                acc[m][t] = __builtin_amdgcn_mfma_f32_16x16x32_bf16(ah[m], bl[t], acc[m][t], 0, 0, 0);
                acc[m][t] = __builtin_amdgcn_mfma_f32_16x16x32_bf16(al[m], bh[t], acc[m][t], 0, 0, 0);
            }
    }

    // C/D: row = q*4 + r, col = l&15  (m89-verified mapping)
    float* po = part + (size_t)kh * NROWS * NEXP;
#pragma unroll
    for (int m = 0; m < 2; m++)
#pragma unroll
        for (int t = 0; t < 4; t++)
#pragma unroll
            for (int r = 0; r < 4; r++)
                po[(size_t)(r0 + m * 16 + q * 4 + r) * NEXP + t * 16 + col] =
                    acc[m][t][r];
}

// One wave per row: sum split-K partials, sigmoid, +bias, top-2 (tie -> lower
// index), normalize. out: [weights 2N][indices-as-float 2N][scores 64N]
__global__ __launch_bounds__(256) void gate_topk_kernel(
    const float* __restrict__ part, const float* __restrict__ bias,
    float* __restrict__ out, int ksplit)
{
    const int tid = threadIdx.x;
    const int e   = tid & 63;
    const int row = blockIdx.x * 4 + (tid >> 6);
    const size_t idx = (size_t)row * NEXP + e;

    float logit = 0.f;
    for (int s = 0; s < ksplit; s++)
        logit += part[(size_t)s * NROWS * NEXP + idx];
    const float score = 1.0f / (1.0f + expf(-logit));
    out[(size_t)4 * NROWS + idx] = score;           // scores

    const float biased = score + bias[e];

    float v = biased; int bi = e;
#pragma unroll
    for (int off = 32; off; off >>= 1) {
        const float ov = __shfl_xor(v, off);
        const int   oi = __shfl_xor(bi, off);
        if (ov > v || (ov == v && oi < bi)) { v = ov; bi = oi; }
    }
    const int i1 = bi;

    float v2 = (e == i1) ? -INFINITY : biased;
    int bi2 = e;
#pragma unroll
    for (int off = 32; off; off >>= 1) {
        const float ov = __shfl_xor(v2, off);
        const int   oi = __shfl_xor(bi2, off);
        if (ov > v2 || (ov == v2 && oi < bi2)) { v2 = ov; bi2 = oi; }
    }
    const int i2 = bi2;

    const float s1 = __shfl(score, i1);
    const float s2 = __shfl(score, i2);
    if (e == 0) {
        const float inv = 1.0f / (s1 + s2);
        out[(size_t)row * 2 + 0] = s1 * inv;
        out[(size_t)row * 2 + 1] = s2 * inv;
        out[(size_t)2 * NROWS + row * 2 + 0] = (float)i1;
        out[(size_t)2 * NROWS + row * 2 + 1] = (float)i2;
    }
}

extern "C" void kernel_launch(void* const* d_in, const int* in_sizes, int n_in,
                              void* d_out, int out_size, void* d_ws, size_t ws_size,
                              hipStream_t stream)
{
    const float* x    = (const float*)d_in[0];
    const float* w    = (const float*)d_in[1];
    const float* bias = (const float*)d_in[2];
    float* out  = (float*)d_out;

    // split-K 16: grid 64x16=1024 blocks (16 waves/CU, 4/SIMD).
    int ksplit = 16;
    const size_t wbytes = (size_t)NEXP * DDIM * 2 * 2;  // whi+wlo, 1 MB
    while (ksplit > 1 &&
           (size_t)ksplit * NROWS * NEXP * 4 + wbytes > ws_size) ksplit >>= 1;

    float* part = (float*)d_ws;
    const size_t part_bytes = (size_t)ksplit * NROWS * NEXP * 4;
    unsigned short* whi = (unsigned short*)((char*)d_ws + part_bytes);
    unsigned short* wlo = whi + (size_t)NEXP * DDIM;

    wfrag_kernel<<<DDIM / 32, 256, 0, stream>>>(w, whi, wlo);
    dim3 g1(NROWS / 128, ksplit);
    gemm_partial_kernel<<<g1, 256, 0, stream>>>(x, whi, wlo, part, ksplit);
    gate_topk_kernel<<<NROWS / 4, 256, 0, stream>>>(part, bias, out, ksplit);
}

// Round 8
// 217.909 us; speedup vs baseline: 1.1551x; 1.1551x over previous
//
#include <hip/hip_runtime.h>
#include <hip/hip_bf16.h>
#include <math.h>

#define NROWS 8192
#define DDIM  4096
#define NEXP  64
#define KSPLIT 16
#define KCHUNK (DDIM / KSPLIT)   // 256
#define KSTEPS (KCHUNK / 32)     // 8  -- compile-time: allocator pipelines it

typedef __attribute__((ext_vector_type(8))) short bf16x8;
typedef __attribute__((ext_vector_type(4))) float f32x4;

__device__ inline unsigned short bf16_rne(float f) {
    unsigned u = __builtin_bit_cast(unsigned, f);
    u += 0x7FFF + ((u >> 16) & 1);
    return (unsigned short)(u >> 16);
}

// split 8 fp32 -> hi/lo bf16 (x = hi + lo + r, |r| <= 2^-18|x|)
__device__ inline void split8(const float* xf, bf16x8& hi, bf16x8& lo) {
#pragma unroll
    for (int j = 0; j < 8; j++) {
        const unsigned short h = bf16_rne(xf[j]);
        const float hf = __builtin_bit_cast(float, (unsigned)h << 16);
        hi[j] = (short)h;
        lo[j] = (short)bf16_rne(xf[j] - hf);
    }
}

// Preconvert W (64 x 4096 fp32) into MFMA B-fragment-linear bf16 hi/lo:
// frag elem j of lane l, tile t, k-chunk kc = B[k=kc*32+(l>>4)*8+j][n=t*16+(l&15)]
// at ((kc*4+t)*64+l)*8. ~1 MB total -> L2/L3-resident for the GEMM.
__global__ __launch_bounds__(256) void wfrag_kernel(
    const float* __restrict__ w, unsigned short* __restrict__ whi,
    unsigned short* __restrict__ wlo)
{
    const int kc = blockIdx.x;            // 0..127
    const int t  = threadIdx.x >> 6;      // n-tile 0..3
    const int l  = threadIdx.x & 63;
    const int e  = t * 16 + (l & 15);
    const int k0 = kc * 32 + ((l >> 4) * 8);
    const float* p = w + (size_t)e * DDIM + k0;
    float xf[8];
    *(float4*)&xf[0] = *(const float4*)p;
    *(float4*)&xf[4] = *(const float4*)(p + 4);
    bf16x8 hi, lo;
    split8(xf, hi, lo);
    const size_t off = ((size_t)(kc * 4 + t) * 64 + l) * 8;
    *(bf16x8*)(whi + off) = hi;
    *(bf16x8*)(wlo + off) = lo;
}

// GEMM: no LDS/barriers. Block = 4 waves; wave = 32 rows (2 m-tiles) x 64
// experts -> each B fragment feeds 2 MFMAs (B L2 traffic halved vs 16-row).
// ALL trip counts compile-time (R7 lesson: runtime ksplit made the allocator
// squeeze to 56 VGPR and spill 120 MB of scratch). Live set ~124 regs.
// Per k32-step: 4 x-loads (HBM, double-buffered) + 8 B-loads (L2, single-
// buffered, hidden behind split8 VALU) + 24 MFMA.
__global__ __launch_bounds__(256) void gemm_partial_kernel(
    const float* __restrict__ x, const unsigned short* __restrict__ whi,
    const unsigned short* __restrict__ wlo, float* __restrict__ part)
{
    const int tid = threadIdx.x;
    const int wv  = tid >> 6;
    const int l   = tid & 63;
    const int q   = l >> 4;
    const int col = l & 15;
    const int r0  = blockIdx.x * 128 + wv * 32;
    const int kh  = blockIdx.y;
    const int kb  = kh * KCHUNK;

    const float* xp0 = x + (size_t)(r0 + col) * DDIM + kb + q * 8;
    const float* xp1 = xp0 + (size_t)16 * DDIM;
    const unsigned short* bhp = whi + ((size_t)(kb / 32) * 4 * 64 + l) * 8;
    const unsigned short* blp = wlo + ((size_t)(kb / 32) * 4 * 64 + l) * 8;

    f32x4 acc[2][4];
#pragma unroll
    for (int m = 0; m < 2; m++)
#pragma unroll
        for (int t = 0; t < 4; t++) acc[m][t] = f32x4{0, 0, 0, 0};

    float xf[2][2][8];                  // [buf][mtile][elem]
    *(float4*)&xf[0][0][0] = *(const float4*)(xp0);
    *(float4*)&xf[0][0][4] = *(const float4*)(xp0 + 4);
    *(float4*)&xf[0][1][0] = *(const float4*)(xp1);
    *(float4*)&xf[0][1][4] = *(const float4*)(xp1 + 4);

    for (int s = 0; s < KSTEPS; s++) {
        const int cur = s & 1, nxt = cur ^ 1;

        bf16x8 bh[4], bl[4];
        const unsigned short* bhs = bhp + (size_t)s * 4 * 64 * 8;
        const unsigned short* bls = blp + (size_t)s * 4 * 64 * 8;
#pragma unroll
        for (int t = 0; t < 4; t++) {
            bh[t] = *(const bf16x8*)(bhs + (size_t)t * 64 * 8);
            bl[t] = *(const bf16x8*)(bls + (size_t)t * 64 * 8);
        }

        if (s + 1 < KSTEPS) {           // prefetch next step's x (HBM)
            const float* xn0 = xp0 + (s + 1) * 32;
            const float* xn1 = xp1 + (s + 1) * 32;
            *(float4*)&xf[nxt][0][0] = *(const float4*)(xn0);
            *(float4*)&xf[nxt][0][4] = *(const float4*)(xn0 + 4);
            *(float4*)&xf[nxt][1][0] = *(const float4*)(xn1);
            *(float4*)&xf[nxt][1][4] = *(const float4*)(xn1 + 4);
        }

        bf16x8 ah[2], al[2];
        split8(xf[cur][0], ah[0], al[0]);
        split8(xf[cur][1], ah[1], al[1]);
#pragma unroll
        for (int m = 0; m < 2; m++)
#pragma unroll
            for (int t = 0; t < 4; t++) {
                acc[m][t] = __builtin_amdgcn_mfma_f32_16x16x32_bf16(ah[m], bh[t], acc[m][t], 0, 0, 0);
                acc[m][t] = __builtin_amdgcn_mfma_f32_16x16x32_bf16(ah[m], bl[t], acc[m][t], 0, 0, 0);
                acc[m][t] = __builtin_amdgcn_mfma_f32_16x16x32_bf16(al[m], bh[t], acc[m][t], 0, 0, 0);
            }
    }

    // C/D: row = q*4 + r, col = l&15  (m89-verified mapping)
    float* po = part + (size_t)kh * NROWS * NEXP;
#pragma unroll
    for (int m = 0; m < 2; m++)
#pragma unroll
        for (int t = 0; t < 4; t++)
#pragma unroll
            for (int r = 0; r < 4; r++)
                po[(size_t)(r0 + m * 16 + q * 4 + r) * NEXP + t * 16 + col] =
                    acc[m][t][r];
}

// One wave per row: sum split-K partials, sigmoid, +bias, top-2 (tie -> lower
// index), normalize. out: [weights 2N][indices-as-float 2N][scores 64N]
__global__ __launch_bounds__(256) void gate_topk_kernel(
    const float* __restrict__ part, const float* __restrict__ bias,
    float* __restrict__ out)
{
    const int tid = threadIdx.x;
    const int e   = tid & 63;
    const int row = blockIdx.x * 4 + (tid >> 6);
    const size_t idx = (size_t)row * NEXP + e;

    float logit = 0.f;
#pragma unroll
    for (int s = 0; s < KSPLIT; s++)
        logit += part[(size_t)s * NROWS * NEXP + idx];
    const float score = 1.0f / (1.0f + expf(-logit));
    out[(size_t)4 * NROWS + idx] = score;           // scores

    const float biased = score + bias[e];

    float v = biased; int bi = e;
#pragma unroll
    for (int off = 32; off; off >>= 1) {
        const float ov = __shfl_xor(v, off);
        const int   oi = __shfl_xor(bi, off);
        if (ov > v || (ov == v && oi < bi)) { v = ov; bi = oi; }
    }
    const int i1 = bi;

    float v2 = (e == i1) ? -INFINITY : biased;
    int bi2 = e;
#pragma unroll
    for (int off = 32; off; off >>= 1) {
        const float ov = __shfl_xor(v2, off);
        const int   oi = __shfl_xor(bi2, off);
        if (ov > v2 || (ov == v2 && oi < bi2)) { v2 = ov; bi2 = oi; }
    }
    const int i2 = bi2;

    const float s1 = __shfl(score, i1);
    const float s2 = __shfl(score, i2);
    if (e == 0) {
        const float inv = 1.0f / (s1 + s2);
        out[(size_t)row * 2 + 0] = s1 * inv;
        out[(size_t)row * 2 + 1] = s2 * inv;
        out[(size_t)2 * NROWS + row * 2 + 0] = (float)i1;
        out[(size_t)2 * NROWS + row * 2 + 1] = (float)i2;
    }
}

extern "C" void kernel_launch(void* const* d_in, const int* in_sizes, int n_in,
                              void* d_out, int out_size, void* d_ws, size_t ws_size,
                              hipStream_t stream)
{
    const float* x    = (const float*)d_in[0];
    const float* w    = (const float*)d_in[1];
    const float* bias = (const float*)d_in[2];
    float* out  = (float*)d_out;

    float* part = (float*)d_ws;                              // 32 MB
    const size_t part_bytes = (size_t)KSPLIT * NROWS * NEXP * 4;
    unsigned short* whi = (unsigned short*)((char*)d_ws + part_bytes);  // 512 KB
    unsigned short* wlo = whi + (size_t)NEXP * DDIM;                    // 512 KB

    wfrag_kernel<<<DDIM / 32, 256, 0, stream>>>(w, whi, wlo);
    dim3 g1(NROWS / 128, KSPLIT);
    gemm_partial_kernel<<<g1, 256, 0, stream>>>(x, whi, wlo, part);
    gate_topk_kernel<<<NROWS / 4, 256, 0, stream>>>(part, bias, out);
}